// Round 3
// baseline (98.337 us; speedup 1.0000x reference)
//
#include <hip/hip_runtime.h>
#include <math.h>

#define N       8192
#define BLK     256
#define MI      2                    // i-tiles (16 rows each) per wave
#define ROWS_PER_BLK (4 * MI * 16)   // 128 rows per block (4 waves)
#define JSTRIP  512                  // columns per block
#define NJT     (JSTRIP / 16)        // 32 j-tiles
#define IB      (N / ROWS_PER_BLK)   // 64 i-blocks
#define JS      (N / JSTRIP)         // 16 j-strips
#define GRID    (IB * JS)            // 1024 blocks

typedef _Float16 half8 __attribute__((ext_vector_type(8)));
typedef float    f32x4 __attribute__((ext_vector_type(4)));

// ------------------------------------------------------------------ prep ----
// Per point: f16 hi/lo split packed into 9 of 32 K-slots (64B record), f32
// norm, dmin=+inf, and counter=0.  A-side k-slots: [ahi(3) alo(3) ahi(3)];
// B-side: [bhi(3) bhi(3) blo(3)]  =>  dot = ahi.bhi + alo.bhi + ahi.blo.
__global__ __launch_bounds__(BLK) void chamfer_prep_kernel(
        const float* __restrict__ tgt, const float* __restrict__ outp,
        _Float16* __restrict__ rec, float* __restrict__ n2,
        unsigned* __restrict__ dmin, unsigned* __restrict__ cnt) {
    int i = blockIdx.x * BLK + (int)threadIdx.x;   // 0 .. 2N-1
    if (i == 0) cnt[0] = 0u;
    int isB = (i >= N);
    int k = isB ? (i - N) : i;
    const float* src = isB ? outp : tgt;
    float x = src[3 * k + 0];
    float y = src[3 * k + 1];
    float z = src[3 * k + 2];
    _Float16 hx = (_Float16)x, hy = (_Float16)y, hz = (_Float16)z;
    _Float16 lx = (_Float16)(x - (float)hx);
    _Float16 ly = (_Float16)(y - (float)hy);
    _Float16 lz = (_Float16)(z - (float)hz);

    alignas(16) _Float16 r[32];
    #pragma unroll
    for (int t = 0; t < 32; ++t) r[t] = (_Float16)0.0f;
    if (!isB) { r[0]=hx; r[1]=hy; r[2]=hz; r[3]=lx; r[4]=ly; r[5]=lz; r[6]=hx; r[7]=hy; r[8]=hz; }
    else      { r[0]=hx; r[1]=hy; r[2]=hz; r[3]=hx; r[4]=hy; r[5]=hz; r[6]=lx; r[7]=ly; r[8]=lz; }

    float4* dst = (float4*)(rec + (size_t)i * 32);
    const float4* sv = (const float4*)r;
    dst[0] = sv[0]; dst[1] = sv[1]; dst[2] = sv[2]; dst[3] = sv[3];

    n2[i] = fmaf(x, x, fmaf(y, y, z * z));
    dmin[i] = 0x7F800000u;   // +inf
}

// ------------------------------------------------------------------ dist ----
// One pass over the 8192x8192 pair matrix via MFMA; fused row-min (dist1)
// and col-min (dist2) epilogue; last block does the sqrt-mean reduction.
__global__ __launch_bounds__(BLK) void chamfer_dist_kernel(
        const half8* __restrict__ rec,   // [2N][4] fragments
        const float* __restrict__ n2,    // a2 [0..N), b2 [N..2N)
        unsigned* __restrict__ dmin,     // dist1 [0..N), dist2 [N..2N)
        unsigned* __restrict__ cnt,
        const int* __restrict__ curp, const int* __restrict__ subp,
        float* __restrict__ out) {
    __shared__ unsigned cm_lds[JSTRIP];
    __shared__ int   lastf;
    __shared__ float red1[4], red2[4];

    int tid  = (int)threadIdx.x;
    int wid  = tid >> 6, lane = tid & 63;
    int c = lane & 15, g = lane >> 4;
    int bi = (int)blockIdx.x % IB;
    int js = (int)blockIdx.x / IB;
    int i0 = bi * ROWS_PER_BLK + wid * (MI * 16);
    int j0base = js * JSTRIP;

    for (int t = tid; t < JSTRIP; t += BLK) cm_lds[t] = 0x7F800000u;
    __syncthreads();

    // A fragments + per-row norms (loaded once)
    half8 af[MI];
    float a2v[MI][4];
    float rm[MI][4];
    #pragma unroll
    for (int m = 0; m < MI; ++m) {
        af[m] = rec[(size_t)(i0 + m * 16 + c) * 4 + g];
        #pragma unroll
        for (int r = 0; r < 4; ++r) {
            a2v[m][r] = n2[i0 + m * 16 + g * 4 + r];
            rm[m][r]  = __builtin_inff();
        }
    }

    const half8* brec = rec + (size_t)N * 4;
    const float* b2   = n2 + N;
    const f32x4 zero = {0.0f, 0.0f, 0.0f, 0.0f};

    for (int jt = 0; jt < NJT; ++jt) {
        int j0 = j0base + jt * 16;
        half8 bf  = brec[(size_t)(j0 + c) * 4 + g];
        float b2j = b2[j0 + c];
        float cm = __builtin_inff();
        #pragma unroll
        for (int m = 0; m < MI; ++m) {
            f32x4 acc = __builtin_amdgcn_mfma_f32_16x16x32_f16(af[m], bf, zero, 0, 0, 0);
            #pragma unroll
            for (int r = 0; r < 4; ++r) {
                float u = fmaf(-2.0f, acc[r], b2j);   // b2_j - 2 a.b
                rm[m][r] = fminf(rm[m][r], u);        // row-min (add a2 later)
                cm = fminf(cm, a2v[m][r] + u);        // col-min
            }
        }
        // col-min across the 4 k-groups (rows), then LDS combine
        cm = fminf(cm, __shfl_xor(cm, 16, 64));
        cm = fminf(cm, __shfl_xor(cm, 32, 64));
        if (lane < 16)
            atomicMin(&cm_lds[jt * 16 + lane], __float_as_uint(fmaxf(cm, 0.0f)));
    }

    // row-min: reduce across the 16 column-lanes, one atomic per row
    #pragma unroll
    for (int m = 0; m < MI; ++m) {
        #pragma unroll
        for (int r = 0; r < 4; ++r) {
            float v = rm[m][r];
            v = fminf(v, __shfl_xor(v, 1, 64));
            v = fminf(v, __shfl_xor(v, 2, 64));
            v = fminf(v, __shfl_xor(v, 4, 64));
            v = fminf(v, __shfl_xor(v, 8, 64));
            if (c == 0) {
                float d2 = fmaxf(a2v[m][r] + v, 0.0f);
                atomicMin(&dmin[i0 + m * 16 + g * 4 + r], __float_as_uint(d2));
            }
        }
    }

    __syncthreads();
    for (int t = tid; t < JSTRIP; t += BLK)
        atomicMin(&dmin[N + j0base + t], cm_lds[t]);

    // ---- last block: fused sqrt-mean reduction ----
    __threadfence();
    if (tid == 0) lastf = (atomicAdd(cnt, 1u) == (unsigned)(gridDim.x - 1));
    __syncthreads();
    if (!lastf) return;

    float s1 = 0.0f, s2 = 0.0f;
    for (int t = tid; t < N; t += BLK) {
        unsigned u1 = __hip_atomic_load(&dmin[t],     __ATOMIC_RELAXED, __HIP_MEMORY_SCOPE_AGENT);
        unsigned u2 = __hip_atomic_load(&dmin[N + t], __ATOMIC_RELAXED, __HIP_MEMORY_SCOPE_AGENT);
        s1 += sqrtf(__uint_as_float(u1));
        s2 += sqrtf(__uint_as_float(u2));
    }
    #pragma unroll
    for (int off = 32; off > 0; off >>= 1) {
        s1 += __shfl_down(s1, off, 64);
        s2 += __shfl_down(s2, off, 64);
    }
    if (lane == 0) { red1[wid] = s1; red2[wid] = s2; }
    __syncthreads();
    if (tid == 0) {
        float t1 = red1[0] + red1[1] + red1[2] + red1[3];
        float t2 = red2[0] + red2[1] + red2[2] + red2[3];
        int e = curp[0] / subp[0];
        double scale = 10.0 / pow(0.99, (double)e);
        out[0] = (float)((((double)t1 + (double)t2) / (double)N) * 0.5 * scale);
    }
}

// ---------------------------------------------------------------- launch ----
extern "C" void kernel_launch(void* const* d_in, const int* in_sizes, int n_in,
                              void* d_out, int out_size, void* d_ws, size_t ws_size,
                              hipStream_t stream) {
    const float* target = (const float*)d_in[0];   // (1, 8192, 3) f32
    const float* output = (const float*)d_in[1];   // (1, 8192, 3) f32
    const int*   curp   = (const int*)d_in[2];
    const int*   subp   = (const int*)d_in[3];
    float* out = (float*)d_out;

    // ws: rec (2N*32 halfs = 1 MB) | n2 (2N f32) | dmin (2N u32) | cnt (u32)
    _Float16* rec  = (_Float16*)d_ws;
    float*    n2   = (float*)(rec + (size_t)2 * N * 32);
    unsigned* dmin = (unsigned*)(n2 + 2 * N);
    unsigned* cnt  = dmin + 2 * N;

    chamfer_prep_kernel<<<2 * N / BLK, BLK, 0, stream>>>(target, output, rec, n2, dmin, cnt);
    chamfer_dist_kernel<<<GRID, BLK, 0, stream>>>((const half8*)rec, n2, dmin, cnt,
                                                  curp, subp, out);
}